// Round 1
// baseline (190.301 us; speedup 1.0000x reference)
//
#include <hip/hip_runtime.h>
#include <math.h>

#define VD 256          // volume is 256^3 fp32 (in_sizes[0] == 16777216)
#define VSHIFT_X 16     // x stride = 256*256
#define VSHIFT_Y 8      // y stride = 256

// ---------------------------------------------------------------------------
// Setup kernel: 1 thread computes M = sdd * ext[:3,:3] @ k_inv and src.
// Writes 12 floats to P: P[0..8] = M row-major, P[9..11] = src.
// ---------------------------------------------------------------------------
__device__ inline void invert4x4(const float* m, float* inv) {
    inv[0]  =  m[5]*m[10]*m[15] - m[5]*m[11]*m[14] - m[9]*m[6]*m[15] + m[9]*m[7]*m[14] + m[13]*m[6]*m[11] - m[13]*m[7]*m[10];
    inv[4]  = -m[4]*m[10]*m[15] + m[4]*m[11]*m[14] + m[8]*m[6]*m[15] - m[8]*m[7]*m[14] - m[12]*m[6]*m[11] + m[12]*m[7]*m[10];
    inv[8]  =  m[4]*m[9]*m[15]  - m[4]*m[11]*m[13] - m[8]*m[5]*m[15] + m[8]*m[7]*m[13] + m[12]*m[5]*m[11] - m[12]*m[7]*m[9];
    inv[12] = -m[4]*m[9]*m[14]  + m[4]*m[10]*m[13] + m[8]*m[5]*m[14] - m[8]*m[6]*m[13] - m[12]*m[5]*m[10] + m[12]*m[6]*m[9];
    inv[1]  = -m[1]*m[10]*m[15] + m[1]*m[11]*m[14] + m[9]*m[2]*m[15] - m[9]*m[3]*m[14] - m[13]*m[2]*m[11] + m[13]*m[3]*m[10];
    inv[5]  =  m[0]*m[10]*m[15] - m[0]*m[11]*m[14] - m[8]*m[2]*m[15] + m[8]*m[3]*m[14] + m[12]*m[2]*m[11] - m[12]*m[3]*m[10];
    inv[9]  = -m[0]*m[9]*m[15]  + m[0]*m[11]*m[13] + m[8]*m[1]*m[15] - m[8]*m[3]*m[13] - m[12]*m[1]*m[11] + m[12]*m[3]*m[9];
    inv[13] =  m[0]*m[9]*m[14]  - m[0]*m[10]*m[13] - m[8]*m[1]*m[14] + m[8]*m[2]*m[13] + m[12]*m[1]*m[10] - m[12]*m[2]*m[9];
    inv[2]  =  m[1]*m[6]*m[15]  - m[1]*m[7]*m[14]  - m[5]*m[2]*m[15] + m[5]*m[3]*m[14] + m[13]*m[2]*m[7]  - m[13]*m[3]*m[6];
    inv[6]  = -m[0]*m[6]*m[15]  + m[0]*m[7]*m[14]  + m[4]*m[2]*m[15] - m[4]*m[3]*m[14] - m[12]*m[2]*m[7]  + m[12]*m[3]*m[6];
    inv[10] =  m[0]*m[5]*m[15]  - m[0]*m[7]*m[13]  - m[4]*m[1]*m[15] + m[4]*m[3]*m[13] + m[12]*m[1]*m[7]  - m[12]*m[3]*m[5];
    inv[14] = -m[0]*m[5]*m[14]  + m[0]*m[6]*m[13]  + m[4]*m[1]*m[14] - m[4]*m[2]*m[13] - m[12]*m[1]*m[6]  + m[12]*m[2]*m[5];
    inv[3]  = -m[1]*m[6]*m[11]  + m[1]*m[7]*m[10]  + m[5]*m[2]*m[11] - m[5]*m[3]*m[10] - m[9]*m[2]*m[7]   + m[9]*m[3]*m[6];
    inv[7]  =  m[0]*m[6]*m[11]  - m[0]*m[7]*m[10]  - m[4]*m[2]*m[11] + m[4]*m[3]*m[10] + m[8]*m[2]*m[7]   - m[8]*m[3]*m[6];
    inv[11] = -m[0]*m[5]*m[11]  + m[0]*m[7]*m[9]   + m[4]*m[1]*m[11] - m[4]*m[3]*m[9]  - m[8]*m[1]*m[7]   + m[8]*m[3]*m[5];
    inv[15] =  m[0]*m[5]*m[10]  - m[0]*m[6]*m[9]   - m[4]*m[1]*m[10] + m[4]*m[2]*m[9]  + m[8]*m[1]*m[6]   - m[8]*m[2]*m[5];
    float det = m[0]*inv[0] + m[1]*inv[4] + m[2]*inv[8] + m[3]*inv[12];
    float rdet = 1.0f / det;
    for (int i = 0; i < 16; i++) inv[i] *= rdet;
}

__global__ void setup_k(const float* __restrict__ iso,
                        const float* __restrict__ rt,
                        const float* __restrict__ kinv,
                        const float* __restrict__ sdd,
                        const float* __restrict__ rot,
                        const float* __restrict__ xyz,
                        float* __restrict__ P) {
    if (threadIdx.x != 0 || blockIdx.x != 0) return;
    float m[16];
    for (int i = 0; i < 16; i++) m[i] = rt[i];
    float minv[16];
    invert4x4(m, minv);
    // c = (inv(rt) @ [iso,1])[:3]
    float c0 = minv[0]*iso[0] + minv[1]*iso[1] + minv[2]*iso[2]  + minv[3];
    float c1 = minv[4]*iso[0] + minv[5]*iso[1] + minv[6]*iso[2]  + minv[7];
    float c2 = minv[8]*iso[0] + minv[9]*iso[1] + minv[10]*iso[2] + minv[11];
    // R = so3_exp(rot)
    float wx = rot[0], wy = rot[1], wz = rot[2];
    float th2 = wx*wx + wy*wy + wz*wz;
    float th = sqrtf(th2);
    float Ac, Bc;
    if (th < 1e-6f) { Ac = 1.0f - th2 / 6.0f; Bc = 0.5f - th2 / 24.0f; }
    else            { Ac = sinf(th) / th;     Bc = (1.0f - cosf(th)) / th2; }
    float R[9];
    R[0] = 1.0f + Bc * (-(wy*wy + wz*wz));
    R[1] = Ac * (-wz) + Bc * (wx*wy);
    R[2] = Ac * ( wy) + Bc * (wx*wz);
    R[3] = Ac * ( wz) + Bc * (wx*wy);
    R[4] = 1.0f + Bc * (-(wx*wx + wz*wz));
    R[5] = Ac * (-wx) + Bc * (wy*wz);
    R[6] = Ac * (-wy) + Bc * (wx*wz);
    R[7] = Ac * ( wx) + Bc * (wy*wz);
    R[8] = 1.0f + Bc * (-(wx*wx + wy*wy));
    // t = R @ xyz
    float tx = R[0]*xyz[0] + R[1]*xyz[1] + R[2]*xyz[2];
    float ty = R[3]*xyz[0] + R[4]*xyz[1] + R[5]*xyz[2];
    float tz = R[6]*xyz[0] + R[7]*xyz[1] + R[8]*xyz[2];
    // pose = [R, c + t - R@c]
    float pt0 = c0 + tx - (R[0]*c0 + R[1]*c1 + R[2]*c2);
    float pt1 = c1 + ty - (R[3]*c0 + R[4]*c1 + R[5]*c2);
    float pt2 = c2 + tz - (R[6]*c0 + R[7]*c1 + R[8]*c2);
    // ext = rt @ pose  (rows 0..2 only; pose row3 = [0,0,0,1])
    float E[12];
    for (int i = 0; i < 3; i++) {
        for (int j = 0; j < 3; j++)
            E[i*4+j] = rt[i*4+0]*R[0*3+j] + rt[i*4+1]*R[1*3+j] + rt[i*4+2]*R[2*3+j];
        E[i*4+3] = rt[i*4+0]*pt0 + rt[i*4+1]*pt1 + rt[i*4+2]*pt2 + rt[i*4+3];
    }
    float s = sdd[0];
    // M = sdd * ext[:3,:3] @ kinv    (seg = M @ [u,v,1])
    for (int i = 0; i < 3; i++)
        for (int j = 0; j < 3; j++)
            P[i*3+j] = s * (E[i*4+0]*kinv[0*3+j] + E[i*4+1]*kinv[1*3+j] + E[i*4+2]*kinv[2*3+j]);
    P[9]  = E[3];
    P[10] = E[7];
    P[11] = E[11];
}

// ---------------------------------------------------------------------------
// Render kernel: one thread per output pixel.
// ---------------------------------------------------------------------------
__global__ __launch_bounds__(256)
void render_k(const float* __restrict__ vol, const float* __restrict__ P,
              const int* __restrict__ pW, const int* __restrict__ pN,
              float* __restrict__ out, int total) {
    int tid = blockIdx.x * 256 + threadIdx.x;
    if (tid >= total) return;
    const int W = pW[0];
    const int N = pN[0];
    int w = tid % W;
    int h = tid / W;
    float u = (float)w + 0.5f;
    float v = (float)h + 0.5f;

    float m0 = P[0], m1 = P[1], m2 = P[2];
    float m3 = P[3], m4 = P[4], m5 = P[5];
    float m6 = P[6], m7 = P[7], m8 = P[8];
    float sx = P[9], sy = P[10], sz = P[11];

    float gx = m0*u + m1*v + m2;
    float gy = m3*u + m4*v + m5;
    float gz = m6*u + m7*v + m8;
    float len = sqrtf(gx*gx + gy*gy + gz*gz);
    float invN = 1.0f / (float)N;

    // Conservative slab clip: trilinear support is coord in (-1, VD).
    // Correctness does NOT depend on this (weights gate out-of-bounds); it
    // only skips samples guaranteed to contribute 0. Padded by 1 sample.
    float t0 = 0.0f, t1 = 1.0f;
    {
        float s3[3] = {sx, sy, sz};
        float g3[3] = {gx, gy, gz};
        for (int a = 0; a < 3; a++) {
            float g = g3[a], s = s3[a];
            if (fabsf(g) > 1e-20f) {
                float ta = (-1.0f - s) / g;
                float tb = ((float)VD - s) / g;
                float lo = fminf(ta, tb), hi = fmaxf(ta, tb);
                t0 = fmaxf(t0, lo);
                t1 = fminf(t1, hi);
            } else if (s <= -1.0f || s >= (float)VD) {
                t1 = -1.0f;  // ray never intersects support
            }
        }
    }
    int k0 = (int)floorf(t0 * (float)N - 0.5f) - 1;
    int k1 = (int)ceilf (t1 * (float)N - 0.5f) + 1;
    if (k0 < 0) k0 = 0;
    if (k1 > N - 1) k1 = N - 1;

    float acc = 0.0f;
    for (int k = k0; k <= k1; k++) {
        float t = ((float)k + 0.5f) * invN;
        float x = fmaf(t, gx, sx);
        float y = fmaf(t, gy, sy);
        float z = fmaf(t, gz, sz);

        float fx = floorf(x); int ix = (int)fx; float ax = x - fx;
        float fy = floorf(y); int iy = (int)fy; float ay = y - fy;
        float fz = floorf(z); int iz = (int)fz; float az = z - fz;

        // per-axis validity folded into weights (constant-0 boundary)
        bool vx0 = (unsigned)ix       < (unsigned)VD;
        bool vx1 = (unsigned)(ix + 1) < (unsigned)VD;
        bool vy0 = (unsigned)iy       < (unsigned)VD;
        bool vy1 = (unsigned)(iy + 1) < (unsigned)VD;
        bool vz0 = (unsigned)iz       < (unsigned)VD;
        bool vz1 = (unsigned)(iz + 1) < (unsigned)VD;
        float wx0 = vx0 ? (1.0f - ax) : 0.0f;
        float wx1 = vx1 ? ax : 0.0f;
        float wy0 = vy0 ? (1.0f - ay) : 0.0f;
        float wy1 = vy1 ? ay : 0.0f;
        float wz0 = vz0 ? (1.0f - az) : 0.0f;
        float wz1 = vz1 ? az : 0.0f;

        // clamped addresses → unconditional loads (weight is 0 when invalid)
        int ix0 = min(max(ix, 0), VD - 1), ix1 = min(max(ix + 1, 0), VD - 1);
        int iy0 = min(max(iy, 0), VD - 1), iy1 = min(max(iy + 1, 0), VD - 1);
        int iz0 = min(max(iz, 0), VD - 1), iz1 = min(max(iz + 1, 0), VD - 1);
        int X0 = ix0 << VSHIFT_X, X1 = ix1 << VSHIFT_X;
        int Y0 = iy0 << VSHIFT_Y, Y1 = iy1 << VSHIFT_Y;

        float v000 = vol[X0 + Y0 + iz0];
        float v001 = vol[X0 + Y0 + iz1];
        float v010 = vol[X0 + Y1 + iz0];
        float v011 = vol[X0 + Y1 + iz1];
        float v100 = vol[X1 + Y0 + iz0];
        float v101 = vol[X1 + Y0 + iz1];
        float v110 = vol[X1 + Y1 + iz0];
        float v111 = vol[X1 + Y1 + iz1];

        float c00 = fmaf(v000, wz0, v001 * wz1);
        float c01 = fmaf(v010, wz0, v011 * wz1);
        float c10 = fmaf(v100, wz0, v101 * wz1);
        float c11 = fmaf(v110, wz0, v111 * wz1);
        float c0  = fmaf(c00, wy0, c01 * wy1);
        float c1  = fmaf(c10, wy0, c11 * wy1);
        acc += fmaf(c0, wx0, c1 * wx1);
    }
    out[tid] = acc * len * invN;
}

extern "C" void kernel_launch(void* const* d_in, const int* in_sizes, int n_in,
                              void* d_out, int out_size, void* d_ws, size_t ws_size,
                              hipStream_t stream) {
    const float* vol  = (const float*)d_in[0];
    const float* iso  = (const float*)d_in[1];
    const float* rt   = (const float*)d_in[2];
    const float* kinv = (const float*)d_in[3];
    const float* sdd  = (const float*)d_in[4];
    const float* rot  = (const float*)d_in[5];
    const float* xyz  = (const float*)d_in[6];
    // d_in[7] = height, d_in[8] = width, d_in[9] = n_samples (device int*)
    const int* pW = (const int*)d_in[8];
    const int* pN = (const int*)d_in[9];
    float* out = (float*)d_out;
    float* P   = (float*)d_ws;

    setup_k<<<1, 64, 0, stream>>>(iso, rt, kinv, sdd, rot, xyz, P);
    int total = out_size;  // 1*1*H*W
    render_k<<<(total + 255) / 256, 256, 0, stream>>>(vol, P, pW, pN, out, total);
}

// Round 2
// 143.186 us; speedup vs baseline: 1.3291x; 1.3291x over previous
//
#include <hip/hip_runtime.h>
#include <math.h>

#define VD 256          // volume is 256^3 fp32
#define VOL_BYTES (VD * VD * VD * 4UL)

// ---------------------------------------------------------------------------
// Setup kernel: 1 thread computes M = sdd * ext[:3,:3] @ k_inv and src.
// Writes 12 floats to P: P[0..8] = M row-major, P[9..11] = src.
// ---------------------------------------------------------------------------
__device__ inline void invert4x4(const float* m, float* inv) {
    inv[0]  =  m[5]*m[10]*m[15] - m[5]*m[11]*m[14] - m[9]*m[6]*m[15] + m[9]*m[7]*m[14] + m[13]*m[6]*m[11] - m[13]*m[7]*m[10];
    inv[4]  = -m[4]*m[10]*m[15] + m[4]*m[11]*m[14] + m[8]*m[6]*m[15] - m[8]*m[7]*m[14] - m[12]*m[6]*m[11] + m[12]*m[7]*m[10];
    inv[8]  =  m[4]*m[9]*m[15]  - m[4]*m[11]*m[13] - m[8]*m[5]*m[15] + m[8]*m[7]*m[13] + m[12]*m[5]*m[11] - m[12]*m[7]*m[9];
    inv[12] = -m[4]*m[9]*m[14]  + m[4]*m[10]*m[13] + m[8]*m[5]*m[14] - m[8]*m[6]*m[13] - m[12]*m[5]*m[10] + m[12]*m[6]*m[9];
    inv[1]  = -m[1]*m[10]*m[15] + m[1]*m[11]*m[14] + m[9]*m[2]*m[15] - m[9]*m[3]*m[14] - m[13]*m[2]*m[11] + m[13]*m[3]*m[10];
    inv[5]  =  m[0]*m[10]*m[15] - m[0]*m[11]*m[14] - m[8]*m[2]*m[15] + m[8]*m[3]*m[14] + m[12]*m[2]*m[11] - m[12]*m[3]*m[10];
    inv[9]  = -m[0]*m[9]*m[15]  + m[0]*m[11]*m[13] + m[8]*m[1]*m[15] - m[8]*m[3]*m[13] - m[12]*m[1]*m[11] + m[12]*m[3]*m[9];
    inv[13] =  m[0]*m[9]*m[14]  - m[0]*m[10]*m[13] - m[8]*m[1]*m[14] + m[8]*m[2]*m[13] + m[12]*m[1]*m[10] - m[12]*m[2]*m[9];
    inv[2]  =  m[1]*m[6]*m[15]  - m[1]*m[7]*m[14]  - m[5]*m[2]*m[15] + m[5]*m[3]*m[14] + m[13]*m[2]*m[7]  - m[13]*m[3]*m[6];
    inv[6]  = -m[0]*m[6]*m[15]  + m[0]*m[7]*m[14]  + m[4]*m[2]*m[15] - m[4]*m[3]*m[14] - m[12]*m[2]*m[7]  + m[12]*m[3]*m[6];
    inv[10] =  m[0]*m[5]*m[15]  - m[0]*m[7]*m[13]  - m[4]*m[1]*m[15] + m[4]*m[3]*m[13] + m[12]*m[1]*m[7]  - m[12]*m[3]*m[5];
    inv[14] = -m[0]*m[5]*m[14]  + m[0]*m[6]*m[13]  + m[4]*m[1]*m[14] - m[4]*m[2]*m[13] - m[12]*m[1]*m[6]  + m[12]*m[2]*m[5];
    inv[3]  = -m[1]*m[6]*m[11]  + m[1]*m[7]*m[10]  + m[5]*m[2]*m[11] - m[5]*m[3]*m[10] - m[9]*m[2]*m[7]   + m[9]*m[3]*m[6];
    inv[7]  =  m[0]*m[6]*m[11]  - m[0]*m[7]*m[10]  - m[4]*m[2]*m[11] + m[4]*m[3]*m[10] + m[8]*m[2]*m[7]   - m[8]*m[3]*m[6];
    inv[11] = -m[0]*m[5]*m[11]  + m[0]*m[7]*m[9]   + m[4]*m[1]*m[11] - m[4]*m[3]*m[9]  - m[8]*m[1]*m[7]   + m[8]*m[3]*m[5];
    inv[15] =  m[0]*m[5]*m[10]  - m[0]*m[6]*m[9]   - m[4]*m[1]*m[10] + m[4]*m[2]*m[9]  + m[8]*m[1]*m[6]   - m[8]*m[2]*m[5];
    float det = m[0]*inv[0] + m[1]*inv[4] + m[2]*inv[8] + m[3]*inv[12];
    float rdet = 1.0f / det;
    for (int i = 0; i < 16; i++) inv[i] *= rdet;
}

__global__ void setup_k(const float* __restrict__ iso,
                        const float* __restrict__ rt,
                        const float* __restrict__ kinv,
                        const float* __restrict__ sdd,
                        const float* __restrict__ rot,
                        const float* __restrict__ xyz,
                        float* __restrict__ P) {
    if (threadIdx.x != 0 || blockIdx.x != 0) return;
    float m[16];
    for (int i = 0; i < 16; i++) m[i] = rt[i];
    float minv[16];
    invert4x4(m, minv);
    float c0 = minv[0]*iso[0] + minv[1]*iso[1] + minv[2]*iso[2]  + minv[3];
    float c1 = minv[4]*iso[0] + minv[5]*iso[1] + minv[6]*iso[2]  + minv[7];
    float c2 = minv[8]*iso[0] + minv[9]*iso[1] + minv[10]*iso[2] + minv[11];
    float wx = rot[0], wy = rot[1], wz = rot[2];
    float th2 = wx*wx + wy*wy + wz*wz;
    float th = sqrtf(th2);
    float Ac, Bc;
    if (th < 1e-6f) { Ac = 1.0f - th2 / 6.0f; Bc = 0.5f - th2 / 24.0f; }
    else            { Ac = sinf(th) / th;     Bc = (1.0f - cosf(th)) / th2; }
    float R[9];
    R[0] = 1.0f + Bc * (-(wy*wy + wz*wz));
    R[1] = Ac * (-wz) + Bc * (wx*wy);
    R[2] = Ac * ( wy) + Bc * (wx*wz);
    R[3] = Ac * ( wz) + Bc * (wx*wy);
    R[4] = 1.0f + Bc * (-(wx*wx + wz*wz));
    R[5] = Ac * (-wx) + Bc * (wy*wz);
    R[6] = Ac * (-wy) + Bc * (wx*wz);
    R[7] = Ac * ( wx) + Bc * (wy*wz);
    R[8] = 1.0f + Bc * (-(wx*wx + wy*wy));
    float tx = R[0]*xyz[0] + R[1]*xyz[1] + R[2]*xyz[2];
    float ty = R[3]*xyz[0] + R[4]*xyz[1] + R[5]*xyz[2];
    float tz = R[6]*xyz[0] + R[7]*xyz[1] + R[8]*xyz[2];
    float pt0 = c0 + tx - (R[0]*c0 + R[1]*c1 + R[2]*c2);
    float pt1 = c1 + ty - (R[3]*c0 + R[4]*c1 + R[5]*c2);
    float pt2 = c2 + tz - (R[6]*c0 + R[7]*c1 + R[8]*c2);
    float E[12];
    for (int i = 0; i < 3; i++) {
        for (int j = 0; j < 3; j++)
            E[i*4+j] = rt[i*4+0]*R[0*3+j] + rt[i*4+1]*R[1*3+j] + rt[i*4+2]*R[2*3+j];
        E[i*4+3] = rt[i*4+0]*pt0 + rt[i*4+1]*pt1 + rt[i*4+2]*pt2 + rt[i*4+3];
    }
    float s = sdd[0];
    for (int i = 0; i < 3; i++)
        for (int j = 0; j < 3; j++)
            P[i*3+j] = s * (E[i*4+0]*kinv[0*3+j] + E[i*4+1]*kinv[1*3+j] + E[i*4+2]*kinv[2*3+j]);
    P[9]  = E[3];
    P[10] = E[7];
    P[11] = E[11];
}

// ---------------------------------------------------------------------------
// Transpose kernel: T[z][y][x] = vol[x][y][z]   (make x the fastest axis)
// Per y-slice, 2D transpose between x and z with a 32x32 LDS tile.
// grid = (8 x-tiles, 8 z-tiles, 256 y), block = (32,8)
// ---------------------------------------------------------------------------
__global__ __launch_bounds__(256)
void transpose_k(const float* __restrict__ in, float* __restrict__ T) {
    __shared__ float tile[32][33];
    const int x0 = blockIdx.x * 32;
    const int z0 = blockIdx.y * 32;
    const int y  = blockIdx.z;
    const int tx = threadIdx.x;        // 0..31
    const int ty = threadIdx.y;        // 0..7
    // read: in[x][y][z], lanes along z (coalesced)
    #pragma unroll
    for (int i = 0; i < 4; i++) {
        int xl = ty + i * 8;
        tile[xl][tx] = in[((x0 + xl) << 16) + (y << 8) + (z0 + tx)];
    }
    __syncthreads();
    // write: T[z][y][x], lanes along x (coalesced)
    #pragma unroll
    for (int i = 0; i < 4; i++) {
        int zl = ty + i * 8;
        T[((z0 + zl) << 16) + (y << 8) + (x0 + tx)] = tile[tx][zl];
    }
}

// ---------------------------------------------------------------------------
// Render kernels: one thread per output pixel.
// Shared ray-march body, parameterized by the axis strides of the layout.
//   direct   : addr = x*65536 + y*256 + z   (SH_X=16, SH_Y=8, z unit)
//   transposed: addr = z*65536 + y*256 + x  (x unit — coalesced across lanes)
// ---------------------------------------------------------------------------
template <int XSH, int YSH, int ZSH>   // log2 strides; unit stride encoded as 0
__device__ inline void render_body(const float* __restrict__ vol,
                                   const float* __restrict__ P,
                                   const int* __restrict__ pW,
                                   const int* __restrict__ pN,
                                   float* __restrict__ out, int total) {
    int tid = blockIdx.x * 256 + threadIdx.x;
    if (tid >= total) return;
    const int W = pW[0];
    const int N = pN[0];
    int w = tid % W;
    int h = tid / W;
    float u = (float)w + 0.5f;
    float v = (float)h + 0.5f;

    float m0 = P[0], m1 = P[1], m2 = P[2];
    float m3 = P[3], m4 = P[4], m5 = P[5];
    float m6 = P[6], m7 = P[7], m8 = P[8];
    float sx = P[9], sy = P[10], sz = P[11];

    float gx = m0*u + m1*v + m2;
    float gy = m3*u + m4*v + m5;
    float gz = m6*u + m7*v + m8;
    float len = sqrtf(gx*gx + gy*gy + gz*gz);
    float invN = 1.0f / (float)N;

    // Conservative slab clip (support is coord in (-1, VD)); weights still
    // gate correctness, this only skips guaranteed-zero samples.
    float t0 = 0.0f, t1 = 1.0f;
    {
        float s3[3] = {sx, sy, sz};
        float g3[3] = {gx, gy, gz};
        for (int a = 0; a < 3; a++) {
            float g = g3[a], s = s3[a];
            if (fabsf(g) > 1e-20f) {
                float ta = (-1.0f - s) / g;
                float tb = ((float)VD - s) / g;
                float lo = fminf(ta, tb), hi = fmaxf(ta, tb);
                t0 = fmaxf(t0, lo);
                t1 = fminf(t1, hi);
            } else if (s <= -1.0f || s >= (float)VD) {
                t1 = -1.0f;
            }
        }
    }
    int k0 = (int)floorf(t0 * (float)N - 0.5f) - 1;
    int k1 = (int)ceilf (t1 * (float)N - 0.5f) + 1;
    if (k0 < 0) k0 = 0;
    if (k1 > N - 1) k1 = N - 1;

    float acc = 0.0f;
    #pragma unroll 2
    for (int k = k0; k <= k1; k++) {
        float t = ((float)k + 0.5f) * invN;
        float x = fmaf(t, gx, sx);
        float y = fmaf(t, gy, sy);
        float z = fmaf(t, gz, sz);

        float fx = floorf(x); int ix = (int)fx; float ax = x - fx;
        float fy = floorf(y); int iy = (int)fy; float ay = y - fy;
        float fz = floorf(z); int iz = (int)fz; float az = z - fz;

        bool vx0 = (unsigned)ix       < (unsigned)VD;
        bool vx1 = (unsigned)(ix + 1) < (unsigned)VD;
        bool vy0 = (unsigned)iy       < (unsigned)VD;
        bool vy1 = (unsigned)(iy + 1) < (unsigned)VD;
        bool vz0 = (unsigned)iz       < (unsigned)VD;
        bool vz1 = (unsigned)(iz + 1) < (unsigned)VD;
        float wx0 = vx0 ? (1.0f - ax) : 0.0f;
        float wx1 = vx1 ? ax : 0.0f;
        float wy0 = vy0 ? (1.0f - ay) : 0.0f;
        float wy1 = vy1 ? ay : 0.0f;
        float wz0 = vz0 ? (1.0f - az) : 0.0f;
        float wz1 = vz1 ? az : 0.0f;

        int ix0 = min(max(ix, 0), VD - 1), ix1 = min(max(ix + 1, 0), VD - 1);
        int iy0 = min(max(iy, 0), VD - 1), iy1 = min(max(iy + 1, 0), VD - 1);
        int iz0 = min(max(iz, 0), VD - 1), iz1 = min(max(iz + 1, 0), VD - 1);
        int X0 = ix0 << XSH, X1 = ix1 << XSH;
        int Y0 = iy0 << YSH, Y1 = iy1 << YSH;
        int Z0 = iz0 << ZSH, Z1 = iz1 << ZSH;

        float v000 = vol[X0 + Y0 + Z0];
        float v001 = vol[X0 + Y0 + Z1];
        float v010 = vol[X0 + Y1 + Z0];
        float v011 = vol[X0 + Y1 + Z1];
        float v100 = vol[X1 + Y0 + Z0];
        float v101 = vol[X1 + Y0 + Z1];
        float v110 = vol[X1 + Y1 + Z0];
        float v111 = vol[X1 + Y1 + Z1];

        float c00 = fmaf(v000, wz0, v001 * wz1);
        float c01 = fmaf(v010, wz0, v011 * wz1);
        float c10 = fmaf(v100, wz0, v101 * wz1);
        float c11 = fmaf(v110, wz0, v111 * wz1);
        float c0  = fmaf(c00, wy0, c01 * wy1);
        float c1  = fmaf(c10, wy0, c11 * wy1);
        acc += fmaf(c0, wx0, c1 * wx1);
    }
    out[tid] = acc * len * invN;
}

__global__ __launch_bounds__(256)
void render_direct(const float* __restrict__ vol, const float* __restrict__ P,
                   const int* __restrict__ pW, const int* __restrict__ pN,
                   float* __restrict__ out, int total) {
    render_body<16, 8, 0>(vol, P, pW, pN, out, total);
}

__global__ __launch_bounds__(256)
void render_transposed(const float* __restrict__ T, const float* __restrict__ P,
                       const int* __restrict__ pW, const int* __restrict__ pN,
                       float* __restrict__ out, int total) {
    // T[z][y][x]: x has unit stride -> lanes (consecutive u) hit contiguous mem
    render_body<0, 8, 16>(T, P, pW, pN, out, total);
}

extern "C" void kernel_launch(void* const* d_in, const int* in_sizes, int n_in,
                              void* d_out, int out_size, void* d_ws, size_t ws_size,
                              hipStream_t stream) {
    const float* vol  = (const float*)d_in[0];
    const float* iso  = (const float*)d_in[1];
    const float* rt   = (const float*)d_in[2];
    const float* kinv = (const float*)d_in[3];
    const float* sdd  = (const float*)d_in[4];
    const float* rot  = (const float*)d_in[5];
    const float* xyz  = (const float*)d_in[6];
    const int* pW = (const int*)d_in[8];
    const int* pN = (const int*)d_in[9];
    float* out = (float*)d_out;
    int total = out_size;

    if (ws_size >= VOL_BYTES + 256) {
        float* T = (float*)d_ws;
        float* P = (float*)((char*)d_ws + VOL_BYTES);
        setup_k<<<1, 64, 0, stream>>>(iso, rt, kinv, sdd, rot, xyz, P);
        transpose_k<<<dim3(8, 8, 256), dim3(32, 8), 0, stream>>>(vol, T);
        render_transposed<<<(total + 255) / 256, 256, 0, stream>>>(T, P, pW, pN, out, total);
    } else {
        float* P = (float*)d_ws;
        setup_k<<<1, 64, 0, stream>>>(iso, rt, kinv, sdd, rot, xyz, P);
        render_direct<<<(total + 255) / 256, 256, 0, stream>>>(vol, P, pW, pN, out, total);
    }
}